// Round 3
// baseline (634.033 us; speedup 1.0000x reference)
//
#include <hip/hip_runtime.h>
#include <hip/hip_cooperative_groups.h>
#include <stdint.h>

namespace cg = cooperative_groups;

// Shapes fixed by the problem: N=16, C=128, H*W=16384, out_chn=128.
#define NB    16
#define CD    128
#define HW    16384
#define KSPLIT 32   // gram K-splits per batch; each block covers HW/KSPLIT = 512

typedef float  f32x4  __attribute__((ext_vector_type(4)));
typedef short  bf16x8 __attribute__((ext_vector_type(8)));

// fp32 -> bf16 round-to-nearest-even (bit trick; proven on this harness)
__device__ __forceinline__ unsigned f2bf(float f) {
    unsigned u = __float_as_uint(f);
    u += 0x7FFFu + ((u >> 16) & 1u);
    return u >> 16;
}
__device__ __forceinline__ unsigned pk2bf(float a, float b) {
    return f2bf(a) | (f2bf(b) << 16);
}

// ---------------------------------------------------------------------------
// FUSED cooperative kernel: 512 blocks x 256 threads, 2 blocks/CU co-resident.
// Phase 1: partial Gram tiles P[kc][n] (register-prefetch pipelined, bf16 MFMA)
// Phase 2: reduce 32 partials/row + softmax -> probs E   (float2 vectorized)
// Phase 3: M[n] = conv_w @ E[n] -> bf16
// Phase 4: out[n] = M[n] @ X[n] + bias (4 l-chunks of 128 pixels per block)
// grid.sync() + __threadfence() between phases (cross-XCD visibility).
// LDS: single 33792 B buffer unioned across phases (gram 128x132, out 128x128
// + 512 B bias).
// ---------------------------------------------------------------------------
__global__ __launch_bounds__(256, 2) void fused_kernel(
    const float* __restrict__ x, const float* __restrict__ cw,
    const float* __restrict__ cb, float* __restrict__ P,
    float* __restrict__ E, unsigned short* __restrict__ Mbf,
    float* __restrict__ out)
{
    const int b    = blockIdx.x;
    const int t    = threadIdx.x;
    const int wv   = t >> 6;
    const int lane = t & 63;
    const int q    = lane >> 4;   // 0..3
    const int r16  = lane & 15;

    __shared__ __align__(16) unsigned short sh[CD * 132];   // 33792 B
    float* bl = (float*)(sh + CD * 128);                    // 512 B tail region

    // ======================= Phase 1: gram =======================
    {
        const int n  = b >> 5;
        const int kc = b & 31;
        unsigned short* Xl = sh;   // [CD][132]

        f32x4 acc[4][4];
#pragma unroll
        for (int i = 0; i < 4; ++i)
#pragma unroll
            for (int j = 0; j < 4; ++j) acc[i][j] = (f32x4)0.0f;

        const int rt0 = 4 * (wv >> 1);
        const int ct0 = 4 * (wv & 1);
        const float* xb = x + (size_t)n * CD * HW;
        const int cS = t >> 5;
        const int lS = (t & 31) * 4;

        float4 stg[16];
#pragma unroll
        for (int i = 0; i < 16; ++i)
            stg[i] = *(const float4*)(xb + (size_t)(i * 8 + cS) * HW + kc * 512 + lS);

        for (int sub = 0; sub < 4; ++sub) {
#pragma unroll
            for (int i = 0; i < 16; ++i) {
                uint2 pk;
                pk.x = pk2bf(stg[i].x, stg[i].y);
                pk.y = pk2bf(stg[i].z, stg[i].w);
                *(uint2*)(&Xl[(i * 8 + cS) * 132 + lS]) = pk;
            }
            __syncthreads();

            if (sub < 3) {
                const int kb = kc * 512 + (sub + 1) * 128;
#pragma unroll
                for (int i = 0; i < 16; ++i)
                    stg[i] = *(const float4*)(xb + (size_t)(i * 8 + cS) * HW + kb + lS);
            }

#pragma unroll
            for (int ks = 0; ks < 4; ++ks) {
                const int k0 = ks * 32 + q * 8;
                bf16x8 af[4], bfr[4];
#pragma unroll
                for (int i = 0; i < 4; ++i) {
                    const unsigned short* pa = &Xl[(16 * (rt0 + i) + r16) * 132 + k0];
                    union { bf16x8 v; uint2 u[2]; } ua;
                    ua.u[0] = *(const uint2*)pa;
                    ua.u[1] = *(const uint2*)(pa + 4);
                    af[i] = ua.v;
                    const unsigned short* pb = &Xl[(16 * (ct0 + i) + r16) * 132 + k0];
                    union { bf16x8 v; uint2 u[2]; } ub;
                    ub.u[0] = *(const uint2*)pb;
                    ub.u[1] = *(const uint2*)(pb + 4);
                    bfr[i] = ub.v;
                }
#pragma unroll
                for (int i = 0; i < 4; ++i)
#pragma unroll
                    for (int j = 0; j < 4; ++j)
                        acc[i][j] = __builtin_amdgcn_mfma_f32_16x16x32_bf16(
                            af[i], bfr[j], acc[i][j], 0, 0, 0);
            }
            __syncthreads();
        }

        float* Pn = P + ((size_t)kc * NB + n) * CD * CD;
#pragma unroll
        for (int i = 0; i < 4; ++i)
#pragma unroll
            for (int j = 0; j < 4; ++j)
#pragma unroll
                for (int rr = 0; rr < 4; ++rr) {
                    // C/D layout (m89): col = lane&15, row = (lane>>4)*4 + reg
                    int row = 16 * (rt0 + i) + q * 4 + rr;
                    int col = 16 * (ct0 + j) + r16;
                    Pn[row * CD + col] = acc[i][j][rr];
                }
    }
    __threadfence();
    cg::this_grid().sync();

    // ======================= Phase 2: reduce + softmax =======================
    {
        const int R   = b * 4 + wv;      // 0..2047
        const int n2  = R >> 7;
        const int row = R & 127;
        const float* p = P + (size_t)n2 * CD * CD + (size_t)row * CD + 2 * lane;
        float s0 = 0.0f, s1 = 0.0f;
#pragma unroll
        for (int kc = 0; kc < KSPLIT; ++kc) {
            const float2 v = *(const float2*)(p + (size_t)kc * NB * CD * CD);
            s0 += v.x; s1 += v.y;
        }
        float m = fmaxf(s0, s1);
#pragma unroll
        for (int off = 32; off > 0; off >>= 1) m = fmaxf(m, __shfl_xor(m, off));
        const float e0 = __expf(s0 - m);
        const float e1 = __expf(s1 - m);
        float e = e0 + e1;
#pragma unroll
        for (int off = 32; off > 0; off >>= 1) e += __shfl_xor(e, off);
        const float inv = 1.0f / e;
        float2 st; st.x = e0 * inv; st.y = e1 * inv;
        *(float2*)(E + (size_t)n2 * CD * CD + (size_t)row * CD + 2 * lane) = st;
    }
    __threadfence();
    cg::this_grid().sync();

    // ======================= Phase 3: M = conv_w @ E =======================
    {
        const int n3 = b >> 5;
        const int o  = (b & 31) * 4 + wv;   // one o per wave
        const int d0 = 2 * lane;
        const float* En  = E + (size_t)n3 * CD * CD + d0;
        const float* cwo = cw + (size_t)o * CD;
        float a0 = 0.0f, a1 = 0.0f;
#pragma unroll 8
        for (int c = 0; c < CD; ++c) {
            const float cv = cwo[c];
            const float2 w = *(const float2*)(En + c * CD);
            a0 += cv * w.x; a1 += cv * w.y;
        }
        *(unsigned*)&Mbf[((size_t)n3 * CD + o) * CD + d0] = pk2bf(a0, a1);
    }
    __threadfence();
    cg::this_grid().sync();

    // ======================= Phase 4: out = M @ X + bias =======================
    {
        unsigned short* Xt = sh;            // [128][128] swizzled, 32 KiB
        if (t < CD) bl[t] = cb[t];

        const int n4 = b >> 5;
        const int lt0 = 4 * (wv >> 1);
        const int ot0 = 4 * (wv & 1);
        const int lt = t & 31;
        const int dg = t >> 5;
        const unsigned short* Mn = Mbf + (size_t)n4 * CD * CD;

        for (int r = 0; r < 4; ++r) {
            const int l0 = ((b & 31) * 4 + r) * 128;
            __syncthreads();   // protect Xt against previous iteration readers

            const float* xb = x + (size_t)n4 * CD * HW + l0;
#pragma unroll
            for (int i = 0; i < 4; ++i) {
                const int d0 = i * 32 + dg * 4;
                const float* bp = xb + (size_t)d0 * HW + 4 * lt;
                float4 v0 = *(const float4*)(bp);
                float4 v1 = *(const float4*)(bp + HW);
                float4 v2 = *(const float4*)(bp + 2 * HW);
                float4 v3 = *(const float4*)(bp + 3 * HW);
                float r0[4] = {v0.x, v0.y, v0.z, v0.w};
                float r1[4] = {v1.x, v1.y, v1.z, v1.w};
                float r2[4] = {v2.x, v2.y, v2.z, v2.w};
                float r3[4] = {v3.x, v3.y, v3.z, v3.w};
                const int dph = d0 ^ (8 * (lt & 7));
#pragma unroll
                for (int j = 0; j < 4; ++j) {
                    uint2 pk;
                    pk.x = pk2bf(r0[j], r1[j]);
                    pk.y = pk2bf(r2[j], r3[j]);
                    *(uint2*)&Xt[(4 * lt + j) * 128 + dph] = pk;
                }
            }
            __syncthreads();

            f32x4 acc[4][4];
#pragma unroll
            for (int i = 0; i < 4; ++i)
#pragma unroll
                for (int j = 0; j < 4; ++j) acc[i][j] = (f32x4)0.0f;

#pragma unroll
            for (int ks = 0; ks < 4; ++ks) {
                const int k0 = ks * 32 + q * 8;
                bf16x8 bfr[4];
#pragma unroll
                for (int j = 0; j < 4; ++j) {
                    const int o = 16 * (ot0 + j) + r16;
                    union { bf16x8 v; uint4 u; } ub;
                    ub.u = *(const uint4*)&Mn[o * CD + k0];
                    bfr[j] = ub.v;
                }
                bf16x8 af[4];
#pragma unroll
                for (int i = 0; i < 4; ++i) {
                    const int l = 16 * (lt0 + i) + r16;
                    const int doff = k0 ^ (8 * ((l >> 2) & 7));
                    union { bf16x8 v; uint4 u; } ua;
                    ua.u = *(const uint4*)&Xt[l * 128 + doff];
                    af[i] = ua.v;
                }
#pragma unroll
                for (int i = 0; i < 4; ++i)
#pragma unroll
                    for (int j = 0; j < 4; ++j)
                        acc[i][j] = __builtin_amdgcn_mfma_f32_16x16x32_bf16(
                            af[i], bfr[j], acc[i][j], 0, 0, 0);
            }

            float* ob = out + (size_t)n4 * CD * HW + l0;
#pragma unroll
            for (int i = 0; i < 4; ++i)
#pragma unroll
                for (int j = 0; j < 4; ++j) {
                    const int o = 16 * (ot0 + j) + r16;
                    const int l = 16 * (lt0 + i) + q * 4;
                    const float bb = bl[o];
                    float4 st;
                    st.x = acc[i][j][0] + bb;
                    st.y = acc[i][j][1] + bb;
                    st.z = acc[i][j][2] + bb;
                    st.w = acc[i][j][3] + bb;
                    *(float4*)(ob + (size_t)o * HW + l) = st;
                }
        }
    }
}

// ---------------------------------------------------------------------------
// Fallback path: the proven 4-kernel pipeline (in case cooperative launch is
// rejected under graph capture). Identical math.
// ---------------------------------------------------------------------------
__global__ __launch_bounds__(256, 2) void gram_kernel(const float* __restrict__ x,
                                                      float* __restrict__ P) {
    const int n  = blockIdx.x;
    const int kc = blockIdx.y;
    const int t    = threadIdx.x;
    const int wv   = t >> 6;
    const int lane = t & 63;
    const int q    = lane >> 4;
    const int r16  = lane & 15;

    __shared__ __align__(16) unsigned short Xl[CD * 132];

    f32x4 acc[4][4];
#pragma unroll
    for (int i = 0; i < 4; ++i)
#pragma unroll
        for (int j = 0; j < 4; ++j) acc[i][j] = (f32x4)0.0f;

    const int rt0 = 4 * (wv >> 1);
    const int ct0 = 4 * (wv & 1);
    const float* xb = x + (size_t)n * CD * HW;
    const int cS = t >> 5;
    const int lS = (t & 31) * 4;

    float4 stg[16];
#pragma unroll
    for (int i = 0; i < 16; ++i)
        stg[i] = *(const float4*)(xb + (size_t)(i * 8 + cS) * HW + kc * 512 + lS);

    for (int sub = 0; sub < 4; ++sub) {
#pragma unroll
        for (int i = 0; i < 16; ++i) {
            uint2 pk;
            pk.x = pk2bf(stg[i].x, stg[i].y);
            pk.y = pk2bf(stg[i].z, stg[i].w);
            *(uint2*)(&Xl[(i * 8 + cS) * 132 + lS]) = pk;
        }
        __syncthreads();
        if (sub < 3) {
            const int kb = kc * 512 + (sub + 1) * 128;
#pragma unroll
            for (int i = 0; i < 16; ++i)
                stg[i] = *(const float4*)(xb + (size_t)(i * 8 + cS) * HW + kb + lS);
        }
#pragma unroll
        for (int ks = 0; ks < 4; ++ks) {
            const int k0 = ks * 32 + q * 8;
            bf16x8 af[4], bfr[4];
#pragma unroll
            for (int i = 0; i < 4; ++i) {
                const unsigned short* pa = &Xl[(16 * (rt0 + i) + r16) * 132 + k0];
                union { bf16x8 v; uint2 u[2]; } ua;
                ua.u[0] = *(const uint2*)pa;
                ua.u[1] = *(const uint2*)(pa + 4);
                af[i] = ua.v;
                const unsigned short* pb = &Xl[(16 * (ct0 + i) + r16) * 132 + k0];
                union { bf16x8 v; uint2 u[2]; } ub;
                ub.u[0] = *(const uint2*)pb;
                ub.u[1] = *(const uint2*)(pb + 4);
                bfr[i] = ub.v;
            }
#pragma unroll
            for (int i = 0; i < 4; ++i)
#pragma unroll
                for (int j = 0; j < 4; ++j)
                    acc[i][j] = __builtin_amdgcn_mfma_f32_16x16x32_bf16(
                        af[i], bfr[j], acc[i][j], 0, 0, 0);
        }
        __syncthreads();
    }

    float* Pn = P + ((size_t)kc * NB + n) * CD * CD;
#pragma unroll
    for (int i = 0; i < 4; ++i)
#pragma unroll
        for (int j = 0; j < 4; ++j)
#pragma unroll
            for (int rr = 0; rr < 4; ++rr) {
                int row = 16 * (rt0 + i) + q * 4 + rr;
                int col = 16 * (ct0 + j) + r16;
                Pn[row * CD + col] = acc[i][j][rr];
            }
}

__global__ __launch_bounds__(256) void reduce_kernel(const float* __restrict__ P,
                                                     float* __restrict__ E) {
    const int R    = blockIdx.x * 4 + (threadIdx.x >> 6);
    const int lane = threadIdx.x & 63;
    const int n    = R >> 7;
    const int row  = R & 127;

    const float* p = P + (size_t)n * CD * CD + (size_t)row * CD + 2 * lane;
    float s0 = 0.0f, s1 = 0.0f;
#pragma unroll
    for (int kc = 0; kc < KSPLIT; ++kc) {
        const float2 v = *(const float2*)(p + (size_t)kc * NB * CD * CD);
        s0 += v.x; s1 += v.y;
    }
    float m = fmaxf(s0, s1);
#pragma unroll
    for (int off = 32; off > 0; off >>= 1) m = fmaxf(m, __shfl_xor(m, off));
    const float e0 = __expf(s0 - m);
    const float e1 = __expf(s1 - m);
    float e = e0 + e1;
#pragma unroll
    for (int off = 32; off > 0; off >>= 1) e += __shfl_xor(e, off);
    const float inv = 1.0f / e;
    float2 st; st.x = e0 * inv; st.y = e1 * inv;
    *(float2*)(E + (size_t)n * CD * CD + (size_t)row * CD + 2 * lane) = st;
}

__global__ __launch_bounds__(256) void mmat_kernel(const float* __restrict__ E,
                                                   const float* __restrict__ cw,
                                                   unsigned short* __restrict__ Mbf) {
    const int n  = blockIdx.x;
    const int bo = blockIdx.y;
    const int t  = threadIdx.x;
    const int o  = bo * 8 + (t >> 5);
    const int d0 = (t & 31) * 4;

    const float* En  = E + (size_t)n * CD * CD;
    const float* cwo = cw + (size_t)o * CD;

    float a0 = 0, a1 = 0, a2 = 0, a3 = 0;
#pragma unroll 8
    for (int c = 0; c < CD; ++c) {
        const float cv = cwo[c];
        float4 w = *(const float4*)&En[c * CD + d0];
        a0 += cv * w.x; a1 += cv * w.y; a2 += cv * w.z; a3 += cv * w.w;
    }
    uint2 pk;
    pk.x = pk2bf(a0, a1);
    pk.y = pk2bf(a2, a3);
    *(uint2*)&Mbf[((size_t)n * CD + o) * CD + d0] = pk;
}

__global__ __launch_bounds__(256) void out_kernel(const float* __restrict__ x,
                                                  const unsigned short* __restrict__ Mbf,
                                                  const float* __restrict__ bias,
                                                  float* __restrict__ out) {
    const int lb = blockIdx.x;
    const int n  = blockIdx.y;
    const int l0 = lb * 128;
    const int t    = threadIdx.x;
    const int wv   = t >> 6;
    const int lane = t & 63;
    const int q    = lane >> 4;
    const int r16  = lane & 15;

    __shared__ __align__(16) unsigned short Xt[128 * 128];
    __shared__ float bl[CD];

    const int lt0 = 4 * (wv >> 1);
    const int ot0 = 4 * (wv & 1);

    if (t < CD) bl[t] = bias[t];

    const float* xb = x + (size_t)n * CD * HW + l0;
    const int lt = t & 31;
    const int dg = t >> 5;
#pragma unroll
    for (int i = 0; i < 4; ++i) {
        const int d0 = i * 32 + dg * 4;
        const float* bp = xb + (size_t)d0 * HW + 4 * lt;
        float4 v0 = *(const float4*)(bp);
        float4 v1 = *(const float4*)(bp + HW);
        float4 v2 = *(const float4*)(bp + 2 * HW);
        float4 v3 = *(const float4*)(bp + 3 * HW);
        float r0[4] = {v0.x, v0.y, v0.z, v0.w};
        float r1[4] = {v1.x, v1.y, v1.z, v1.w};
        float r2[4] = {v2.x, v2.y, v2.z, v2.w};
        float r3[4] = {v3.x, v3.y, v3.z, v3.w};
        const int dph = d0 ^ (8 * (lt & 7));
#pragma unroll
        for (int j = 0; j < 4; ++j) {
            uint2 pk;
            pk.x = pk2bf(r0[j], r1[j]);
            pk.y = pk2bf(r2[j], r3[j]);
            *(uint2*)&Xt[(4 * lt + j) * 128 + dph] = pk;
        }
    }
    __syncthreads();

    f32x4 acc[4][4];
#pragma unroll
    for (int i = 0; i < 4; ++i)
#pragma unroll
        for (int j = 0; j < 4; ++j) acc[i][j] = (f32x4)0.0f;

    const unsigned short* Mn = Mbf + (size_t)n * CD * CD;
#pragma unroll
    for (int ks = 0; ks < 4; ++ks) {
        const int k0 = ks * 32 + q * 8;
        bf16x8 bfr[4];
#pragma unroll
        for (int j = 0; j < 4; ++j) {
            const int o = 16 * (ot0 + j) + r16;
            union { bf16x8 v; uint4 u; } ub;
            ub.u = *(const uint4*)&Mn[o * CD + k0];
            bfr[j] = ub.v;
        }
        bf16x8 af[4];
#pragma unroll
        for (int i = 0; i < 4; ++i) {
            const int l = 16 * (lt0 + i) + r16;
            const int doff = k0 ^ (8 * ((l >> 2) & 7));
            union { bf16x8 v; uint4 u; } ua;
            ua.u = *(const uint4*)&Xt[l * 128 + doff];
            af[i] = ua.v;
        }
#pragma unroll
        for (int i = 0; i < 4; ++i)
#pragma unroll
            for (int j = 0; j < 4; ++j)
                acc[i][j] = __builtin_amdgcn_mfma_f32_16x16x32_bf16(
                    af[i], bfr[j], acc[i][j], 0, 0, 0);
    }

    float* ob = out + (size_t)n * CD * HW + l0;
#pragma unroll
    for (int i = 0; i < 4; ++i)
#pragma unroll
        for (int j = 0; j < 4; ++j) {
            const int o = 16 * (ot0 + j) + r16;
            const int l = 16 * (lt0 + i) + q * 4;
            const float bb = bl[o];
            float4 st;
            st.x = acc[i][j][0] + bb;
            st.y = acc[i][j][1] + bb;
            st.z = acc[i][j][2] + bb;
            st.w = acc[i][j][3] + bb;
            *(float4*)(ob + (size_t)o * HW + l) = st;
        }
}

// ---------------------------------------------------------------------------
extern "C" void kernel_launch(void* const* d_in, const int* in_sizes, int n_in,
                              void* d_out, int out_size, void* d_ws, size_t ws_size,
                              hipStream_t stream) {
    const float* x  = (const float*)d_in[0];   // (16,128,128,128) fp32
    const float* cw = (const float*)d_in[1];   // (128,128) fp32
    const float* cb = (const float*)d_in[2];   // (128,) fp32
    float* out = (float*)d_out;                // (16,128,128,128) fp32

    char* ws = (char*)d_ws;
    float*          P   = (float*)(ws);                // 32 MiB partials
    float*          E   = (float*)(ws + (32u << 20));  // 1 MiB softmax probs
    unsigned short* Mbf = (unsigned short*)(ws + (33u << 20)); // 512 KiB

    void* args[] = {(void*)&x, (void*)&cw, (void*)&cb, (void*)&P,
                    (void*)&E, (void*)&Mbf, (void*)&out};
    hipError_t err = hipLaunchCooperativeKernel(fused_kernel, dim3(512), dim3(256),
                                                args, 0, stream);
    if (err != hipSuccess) {
        // graph-capture or capacity rejection -> proven 4-kernel path
        gram_kernel   <<<dim3(NB, KSPLIT), 256, 0, stream>>>(x, P);
        reduce_kernel <<<dim3(512),        256, 0, stream>>>(P, E);
        mmat_kernel   <<<dim3(NB, 16),     256, 0, stream>>>(E, cw, Mbf);
        out_kernel    <<<dim3(128, NB),    256, 0, stream>>>(x, Mbf, cb, out);
    }
}

// Round 4
// 300.806 us; speedup vs baseline: 2.1078x; 2.1078x over previous
//
#include <hip/hip_runtime.h>
#include <stdint.h>

// Shapes fixed by the problem: N=16, C=128, H*W=16384, out_chn=128.
#define NB    16
#define CD    128
#define HW    16384
#define KSPLIT 32   // gram K-splits per batch; each block covers HW/KSPLIT = 512

typedef float  f32x4  __attribute__((ext_vector_type(4)));
typedef short  bf16x8 __attribute__((ext_vector_type(8)));

// fp32 -> bf16 round-to-nearest-even (bit trick; proven on this harness)
__device__ __forceinline__ unsigned f2bf(float f) {
    unsigned u = __float_as_uint(f);
    u += 0x7FFFu + ((u >> 16) & 1u);
    return u >> 16;
}
__device__ __forceinline__ unsigned pk2bf(float a, float b) {
    return f2bf(a) | (f2bf(b) << 16);
}

// ---------------------------------------------------------------------------
// Kernel 1: partial Gram tiles. P[kc][n] = X[:, kc*512:(kc+1)*512] @ (same)^T
// grid (16 n, 32 kc), 256 threads, 2 blocks/CU.
// R4 changes (R3 fused-run counters showed traffic is already minimal; cost
// is structure): (a) XOR-swizzled LDS layout phys(c,k)=c*128+(k^(8*(c&7)))
// -> fragment reads become single ds_read_b128 (was 2x b64 against pad-132),
// 2-way conflicts = free; (b) LDS double-buffer (2x32 KiB) -> ONE barrier per
// sub instead of two: write buf[next] after MFMA of buf[cur], barrier at loop
// top only. Register prefetch (T14) retained. Math bit-identical to R2.
// ---------------------------------------------------------------------------
__global__ __launch_bounds__(256, 2) void gram_kernel(const float* __restrict__ x,
                                                      float* __restrict__ P) {
    const int n  = blockIdx.x;
    const int kc = blockIdx.y;
    const int t    = threadIdx.x;
    const int wv   = t >> 6;
    const int lane = t & 63;
    const int q    = lane >> 4;   // 0..3
    const int r16  = lane & 15;

    __shared__ __align__(16) unsigned short Xl[2 * CD * 128];   // 64 KiB dbuf

    f32x4 acc[4][4];
#pragma unroll
    for (int i = 0; i < 4; ++i)
#pragma unroll
        for (int j = 0; j < 4; ++j) acc[i][j] = (f32x4)0.0f;

    const int rt0 = 4 * (wv >> 1);   // row-tile base (of 8 16-wide tiles)
    const int ct0 = 4 * (wv & 1);    // col-tile base

    const float* xb = x + (size_t)n * CD * HW;

    // staging decomposition: c = i*8 + cS, k-offset lS = (t&31)*4 (4-aligned)
    const int cS  = t >> 5;               // 0..7  (== c&7 for every staged row)
    const int lS  = (t & 31) * 4;
    const int wsw = lS ^ (8 * cS);        // swizzled write offset (8-block XOR
                                          // preserves 4-element runs)
    const int rx  = 8 * (r16 & 7);        // read-side XOR: row&7 == r16&7

    float4 stg[16];
#pragma unroll
    for (int i = 0; i < 16; ++i)
        stg[i] = *(const float4*)(xb + (size_t)(i * 8 + cS) * HW + kc * 512 + lS);
#pragma unroll
    for (int i = 0; i < 16; ++i) {
        uint2 pk;
        pk.x = pk2bf(stg[i].x, stg[i].y);
        pk.y = pk2bf(stg[i].z, stg[i].w);
        *(uint2*)(&Xl[(i * 8 + cS) * 128 + wsw]) = pk;
    }

    for (int sub = 0; sub < 4; ++sub) {
        // issue next sub's global loads first: latency hides under MFMA phase
        if (sub < 3) {
            const int kb = kc * 512 + (sub + 1) * 128;
#pragma unroll
            for (int i = 0; i < 16; ++i)
                stg[i] = *(const float4*)(xb + (size_t)(i * 8 + cS) * HW + kb + lS);
        }
        __syncthreads();   // buf[sub&1] writes (prev iter / prologue) visible

        const unsigned short* Xc = &Xl[(size_t)(sub & 1) * CD * 128];
#pragma unroll
        for (int ks = 0; ks < 4; ++ks) {
            const int ko = (ks * 32 + q * 8) ^ rx;
            bf16x8 af[4], bfr[4];
#pragma unroll
            for (int i = 0; i < 4; ++i) {
                union { bf16x8 v; uint4 u; } ua;
                ua.u = *(const uint4*)&Xc[(16 * (rt0 + i) + r16) * 128 + ko];
                af[i] = ua.v;
                union { bf16x8 v; uint4 u; } ub;
                ub.u = *(const uint4*)&Xc[(16 * (ct0 + i) + r16) * 128 + ko];
                bfr[i] = ub.v;
            }
#pragma unroll
            for (int i = 0; i < 4; ++i)
#pragma unroll
                for (int j = 0; j < 4; ++j)
                    acc[i][j] = __builtin_amdgcn_mfma_f32_16x16x32_bf16(
                        af[i], bfr[j], acc[i][j], 0, 0, 0);
        }

        // convert + write NEXT buffer; its readers barrier at next loop top.
        if (sub < 3) {
            unsigned short* Xn = &Xl[(size_t)((sub + 1) & 1) * CD * 128];
#pragma unroll
            for (int i = 0; i < 16; ++i) {
                uint2 pk;
                pk.x = pk2bf(stg[i].x, stg[i].y);
                pk.y = pk2bf(stg[i].z, stg[i].w);
                *(uint2*)(&Xn[(i * 8 + cS) * 128 + wsw]) = pk;
            }
        }
    }

    float* Pn = P + ((size_t)kc * NB + n) * CD * CD;
#pragma unroll
    for (int i = 0; i < 4; ++i)
#pragma unroll
        for (int j = 0; j < 4; ++j)
#pragma unroll
            for (int rr = 0; rr < 4; ++rr) {
                // C/D layout (m89): col = lane&15, row = (lane>>4)*4 + reg
                int row = 16 * (rt0 + i) + q * 4 + rr;
                int col = 16 * (ct0 + j) + r16;
                Pn[row * CD + col] = acc[i][j][rr];
            }
}

// ---------------------------------------------------------------------------
// Kernel 2: reduce 32 partials per G-row and emit softmax PROBS directly
// (E = exp(s-m)/sum). One wave per row; 2048 rows -> 512 blocks x 256 threads.
// ---------------------------------------------------------------------------
__global__ __launch_bounds__(256) void reduce_kernel(const float* __restrict__ P,
                                                     float* __restrict__ E) {
    const int R    = blockIdx.x * 4 + (threadIdx.x >> 6);
    const int lane = threadIdx.x & 63;
    const int n    = R >> 7;
    const int row  = R & 127;

    const float* p = P + (size_t)n * CD * CD + (size_t)row * CD + 2 * lane;
    float s0 = 0.0f, s1 = 0.0f;
#pragma unroll
    for (int kc = 0; kc < KSPLIT; ++kc) {
        const float2 v = *(const float2*)(p + (size_t)kc * NB * CD * CD);
        s0 += v.x; s1 += v.y;
    }
    float m = fmaxf(s0, s1);
#pragma unroll
    for (int off = 32; off > 0; off >>= 1) m = fmaxf(m, __shfl_xor(m, off));
    const float e0 = __expf(s0 - m);
    const float e1 = __expf(s1 - m);
    float e = e0 + e1;
#pragma unroll
    for (int off = 32; off > 0; off >>= 1) e += __shfl_xor(e, off);
    const float inv = 1.0f / e;
    float2 st; st.x = e0 * inv; st.y = e1 * inv;
    *(float2*)(E + (size_t)n * CD * CD + (size_t)row * CD + 2 * lane) = st;
}

// ---------------------------------------------------------------------------
// Kernel 3: M[n] = conv_w @ E[n]  -> bf16.  256 blocks, no LDS, no barrier.
// ---------------------------------------------------------------------------
__global__ __launch_bounds__(256) void mmat_kernel(const float* __restrict__ E,
                                                   const float* __restrict__ cw,
                                                   unsigned short* __restrict__ Mbf) {
    const int n  = blockIdx.x;
    const int bo = blockIdx.y;
    const int t  = threadIdx.x;
    const int o  = bo * 8 + (t >> 5);
    const int d0 = (t & 31) * 4;

    const float* En  = E + (size_t)n * CD * CD;
    const float* cwo = cw + (size_t)o * CD;

    float a0 = 0, a1 = 0, a2 = 0, a3 = 0;
#pragma unroll 8
    for (int c = 0; c < CD; ++c) {
        const float cv = cwo[c];
        float4 w = *(const float4*)&En[c * CD + d0];
        a0 += cv * w.x; a1 += cv * w.y; a2 += cv * w.z; a3 += cv * w.w;
    }
    uint2 pk;
    pk.x = pk2bf(a0, a1);
    pk.y = pk2bf(a2, a3);
    *(uint2*)&Mbf[((size_t)n * CD + o) * CD + d0] = pk;
}

// ---------------------------------------------------------------------------
// Kernel 4: out[n] = M[n] @ X[n] + bias, computed as D[l][o] = sum_c X[c][l]M[o][c].
// A-operand = X^T from LDS (XOR-swizzled, pad-free, b128 reads); B-operand = M
// straight from global (contiguous, L2-hot). Epilogue: float4 stores (l-contig).
// Swizzle: phys(l, d) = l*128 + (d ^ (8*((l>>2)&7))), preserves 8-aligned runs.
// ---------------------------------------------------------------------------
__global__ __launch_bounds__(256) void out_kernel(const float* __restrict__ x,
                                                  const unsigned short* __restrict__ Mbf,
                                                  const float* __restrict__ bias,
                                                  float* __restrict__ out) {
    const int lb = blockIdx.x;      // 128 chunks of 128 pixels
    const int n  = blockIdx.y;
    const int l0 = lb * 128;
    const int t    = threadIdx.x;
    const int wv   = t >> 6;
    const int lane = t & 63;
    const int q    = lane >> 4;
    const int r16  = lane & 15;

    __shared__ __align__(16) unsigned short Xt[128 * 128];  // 32 KiB, swizzled
    __shared__ float bl[CD];

    const int lt0 = 4 * (wv >> 1);   // l-tile base (D rows)
    const int ot0 = 4 * (wv & 1);    // o-tile base (D cols)

    if (t < CD) bl[t] = bias[t];

    // Stage X[n][d][l0..l0+127] fp32 -> bf16, transposed via 4x4 register tiles
    const float* xb = x + (size_t)n * CD * HW + l0;
    const int lt = t & 31;
    const int dg = t >> 5;
#pragma unroll
    for (int i = 0; i < 4; ++i) {
        const int d0 = i * 32 + dg * 4;
        const float* bp = xb + (size_t)d0 * HW + 4 * lt;
        float4 v0 = *(const float4*)(bp);
        float4 v1 = *(const float4*)(bp + HW);
        float4 v2 = *(const float4*)(bp + 2 * HW);
        float4 v3 = *(const float4*)(bp + 3 * HW);
        float r0[4] = {v0.x, v0.y, v0.z, v0.w};
        float r1[4] = {v1.x, v1.y, v1.z, v1.w};
        float r2[4] = {v2.x, v2.y, v2.z, v2.w};
        float r3[4] = {v3.x, v3.y, v3.z, v3.w};
        const int dph = d0 ^ (8 * (lt & 7));
#pragma unroll
        for (int j = 0; j < 4; ++j) {
            uint2 pk;
            pk.x = pk2bf(r0[j], r1[j]);
            pk.y = pk2bf(r2[j], r3[j]);
            *(uint2*)&Xt[(4 * lt + j) * 128 + dph] = pk;
        }
    }
    __syncthreads();

    f32x4 acc[4][4];
#pragma unroll
    for (int i = 0; i < 4; ++i)
#pragma unroll
        for (int j = 0; j < 4; ++j) acc[i][j] = (f32x4)0.0f;

    const unsigned short* Mn = Mbf + (size_t)n * CD * CD;
#pragma unroll
    for (int ks = 0; ks < 4; ++ks) {
        const int k0 = ks * 32 + q * 8;
        // B-frags: B[k=c][col=o] = M[o][c] -> contiguous 16B from global
        bf16x8 bfr[4];
#pragma unroll
        for (int j = 0; j < 4; ++j) {
            const int o = 16 * (ot0 + j) + r16;
            union { bf16x8 v; uint4 u; } ub;
            ub.u = *(const uint4*)&Mn[o * CD + k0];
            bfr[j] = ub.v;
        }
        // A-frags: A[m=l][k=c] = X[c][l] from swizzled LDS, b128
        bf16x8 af[4];
#pragma unroll
        for (int i = 0; i < 4; ++i) {
            const int l = 16 * (lt0 + i) + r16;
            const int doff = k0 ^ (8 * ((l >> 2) & 7));
            union { bf16x8 v; uint4 u; } ua;
            ua.u = *(const uint4*)&Xt[l * 128 + doff];
            af[i] = ua.v;
        }
#pragma unroll
        for (int i = 0; i < 4; ++i)
#pragma unroll
            for (int j = 0; j < 4; ++j)
                acc[i][j] = __builtin_amdgcn_mfma_f32_16x16x32_bf16(
                    af[i], bfr[j], acc[i][j], 0, 0, 0);
    }

    // D[row=l][col=o]: lane holds col o=r16-within-tile, rows q*4+rr -> l-contig
    float* ob = out + (size_t)n * CD * HW + l0;
#pragma unroll
    for (int i = 0; i < 4; ++i)
#pragma unroll
        for (int j = 0; j < 4; ++j) {
            const int o = 16 * (ot0 + j) + r16;
            const int l = 16 * (lt0 + i) + q * 4;
            const float b = bl[o];
            float4 st;
            st.x = acc[i][j][0] + b;
            st.y = acc[i][j][1] + b;
            st.z = acc[i][j][2] + b;
            st.w = acc[i][j][3] + b;
            *(float4*)(ob + (size_t)o * HW + l) = st;
        }
}

// ---------------------------------------------------------------------------
extern "C" void kernel_launch(void* const* d_in, const int* in_sizes, int n_in,
                              void* d_out, int out_size, void* d_ws, size_t ws_size,
                              hipStream_t stream) {
    const float* x  = (const float*)d_in[0];   // (16,128,128,128) fp32
    const float* cw = (const float*)d_in[1];   // (128,128) fp32
    const float* cb = (const float*)d_in[2];   // (128,) fp32
    float* out = (float*)d_out;                // (16,128,128,128) fp32

    char* ws = (char*)d_ws;
    float*          P   = (float*)(ws);                // 32 MiB partials
    float*          E   = (float*)(ws + (32u << 20));  // 1 MiB softmax probs
    unsigned short* Mbf = (unsigned short*)(ws + (33u << 20)); // 512 KiB

    gram_kernel   <<<dim3(NB, KSPLIT), 256, 0, stream>>>(x, P);
    reduce_kernel <<<dim3(512),        256, 0, stream>>>(P, E);
    mmat_kernel   <<<dim3(NB, 16),     256, 0, stream>>>(E, cw, Mbf);
    out_kernel    <<<dim3(128, NB),    256, 0, stream>>>(x, Mbf, cb, out);
}